// Round 5
// baseline (143.445 us; speedup 1.0000x reference)
//
#include <hip/hip_runtime.h>

// QueryAndGroup: ball_query(r=0.2, ns=32) + group xyz (centered) + group features.
//   xyz      [8][16384][3] f32   d_in[0]
//   new_xyz  [8][1024][3]  f32   d_in[1]
//   features [8][64][16384] f32  d_in[2]
//   out      [8][67][1024][32] f32
//
// R3 evidence: qg_main 51us @ 21% HBM, VALU 11%, occupancy 28% -> latency bound.
// Fixes: (a) wave-synchronous LDS, zero __syncthreads, 4 indep waves/block;
// (b) software-pipelined phase-1 scan (prefetch next 128 pts before ballots);
// (c) dwordx4 nontemporal output stores (1KB/instr, no L2/L3 pollution);
// (d) XCD swizzle: blockIdx&7 = batch -> each XCD's 4MiB L2 holds its batch's
//     4MB transposed-feature slab; (e) hit coords cached in LDS at ballot time.
// R4 fix: __builtin_nontemporal_* needs a clang ext-vector, not HIP float4.

#define N_PTS   16384
#define M_Q     1024
#define B_SZ    8
#define NSAMP   32
#define NCH     64
#define R2      0.04f
#define OUT_CH  (3 + NCH)

typedef float f4 __attribute__((ext_vector_type(4)));   // native vector: nt-builtin OK

// ---------- features [B][C][N] -> ft [B][N][C] ----------
__global__ __launch_bounds__(256) void transpose_kernel(
    const float* __restrict__ feat, float* __restrict__ ft)
{
    __shared__ float tile[64][65];                 // +1 pad
    const int b   = blockIdx.x & 7;                // XCD swizzle: batch = blockIdx % 8
    const int n0  = (blockIdx.x >> 3) << 6;
    const int tid = threadIdx.x;
    const float* __restrict__ fb = feat + (size_t)b * NCH * N_PTS;
    float* __restrict__ tb       = ft   + ((size_t)b * N_PTS + n0) * NCH;

#pragma unroll
    for (int j = 0; j < 16; ++j) {                 // read coalesced along n (single-use -> nt)
        const int idx = j * 256 + tid;
        const int c = idx >> 6, nn = idx & 63;
        tile[c][nn] = __builtin_nontemporal_load(&fb[(size_t)c * N_PTS + n0 + nn]);
    }
    __syncthreads();
    const int c4 = tid & 15;                       // float4 slot along c
    const int r  = tid >> 4;
#pragma unroll
    for (int j = 0; j < 4; ++j) {                  // write: 1KB dwordx4 per instr
        const int nn = j * 16 + r;
        f4 o;
        o.x = tile[c4 * 4 + 0][nn];
        o.y = tile[c4 * 4 + 1][nn];
        o.z = tile[c4 * 4 + 2][nn];
        o.w = tile[c4 * 4 + 3][nn];
        *(f4*)(&tb[(size_t)nn * NCH + c4 * 4]) = o;  // ft re-read later: keep cached
    }
}

// ---------- main: ball query + grouped gather from ft [B][N][C] ----------
// 4 waves/block, one query per wave, NO __syncthreads (all LDS per-wave).
__global__ __launch_bounds__(256) void qg_main(
    const float* __restrict__ xyz,      // [B][N][3]
    const float* __restrict__ new_xyz,  // [B][M][3]
    const float* __restrict__ ft,       // [B][N][C]
    float* __restrict__ out)            // [B][67][M][NS]
{
    const int tid  = threadIdx.x;
    const int w    = tid >> 6;
    const int lane = tid & 63;
    const int b    = blockIdx.x & 7;               // XCD swizzle
    const int m    = ((blockIdx.x >> 3) << 2) + w;
    const int q    = (b << 10) + m;

    __shared__ float pxyz[4][NSAMP][4];            // [wave][slot] = {x, y, z, bits(idx)}
    __shared__ float tile[4][32][33];              // [wave][c_local][s]

    const float cx = new_xyz[q * 3 + 0];
    const float cy = new_xyz[q * 3 + 1];
    const float cz = new_xyz[q * 3 + 2];
    const float* __restrict__ xb = xyz + (size_t)b * N_PTS * 3;

    // ---- Phase 1: ordered ball query, software-pipelined 2x64 chunks ----
    const unsigned long long lmask = (1ull << lane) - 1ull;
    int cnt = 0;
    float Ax = xb[lane * 3 + 0],        Ay = xb[lane * 3 + 1],        Az = xb[lane * 3 + 2];
    float Bx = xb[(64 + lane) * 3 + 0], By = xb[(64 + lane) * 3 + 1], Bz = xb[(64 + lane) * 3 + 2];

    for (int base = 0; ; base += 128) {
        // prefetch next 128 points before touching this iteration's ballots
        const int  nbase = base + 128;
        const bool more  = nbase < N_PTS;
        const int  pA = more ? nbase + lane : lane;       // dummy reload if done (L1 hit)
        const int  pB = pA + 64;
        const float nAx = xb[pA * 3 + 0], nAy = xb[pA * 3 + 1], nAz = xb[pA * 3 + 2];
        const float nBx = xb[pB * 3 + 0], nBy = xb[pB * 3 + 1], nBz = xb[pB * 3 + 2];

        {   // chunk A (index order before B)
            const float dx = __fsub_rn(cx, Ax), dy = __fsub_rn(cy, Ay), dz = __fsub_rn(cz, Az);
            const float d2 = __fadd_rn(__fadd_rn(__fmul_rn(dx, dx), __fmul_rn(dy, dy)),
                                       __fmul_rn(dz, dz));
            const bool hit = d2 < R2;
            const unsigned long long mk = __ballot(hit);
            if (hit) {
                const int slot = cnt + __popcll(mk & lmask);
                if (slot < NSAMP) {
                    pxyz[w][slot][0] = Ax;
                    pxyz[w][slot][1] = Ay;
                    pxyz[w][slot][2] = Az;
                    pxyz[w][slot][3] = __int_as_float(base + lane);
                }
            }
            cnt += (int)__popcll(mk);
        }
        {   // chunk B
            const float dx = __fsub_rn(cx, Bx), dy = __fsub_rn(cy, By), dz = __fsub_rn(cz, Bz);
            const float d2 = __fadd_rn(__fadd_rn(__fmul_rn(dx, dx), __fmul_rn(dy, dy)),
                                       __fmul_rn(dz, dz));
            const bool hit = d2 < R2;
            const unsigned long long mk = __ballot(hit);
            if (hit) {
                const int slot = cnt + __popcll(mk & lmask);
                if (slot < NSAMP) {
                    pxyz[w][slot][0] = Bx;
                    pxyz[w][slot][1] = By;
                    pxyz[w][slot][2] = Bz;
                    pxyz[w][slot][3] = __int_as_float(base + 64 + lane);
                }
            }
            cnt += (int)__popcll(mk);
        }
        if (cnt >= NSAMP || !more) break;
        Ax = nAx; Ay = nAy; Az = nAz;
        Bx = nBx; By = nBy; Bz = nBz;
    }

    // fill empty slots with slot 0 (reference broadcasts sorted_idx[...,0])
    if (lane < NSAMP && cnt < NSAMP) {
        float v0x, v0y, v0z, v0w;
        if (cnt > 0) {
            v0x = pxyz[w][0][0]; v0y = pxyz[w][0][1];
            v0z = pxyz[w][0][2]; v0w = pxyz[w][0][3];
        } else {
            v0x = xb[0]; v0y = xb[1]; v0z = xb[2]; v0w = __int_as_float(0);
        }
        if (lane >= cnt) {
            pxyz[w][lane][0] = v0x; pxyz[w][lane][1] = v0y;
            pxyz[w][lane][2] = v0z; pxyz[w][lane][3] = v0w;
        }
    }
    // wave-synchronous: same-wave ds_write -> ds_read ordered by lgkmcnt

    float* __restrict__ ob = out + ((size_t)b * OUT_CH * M_Q + (size_t)m) * NSAMP;

    // ---- Phase 2a: centered xyz channels straight from LDS (24 lanes, 1 dwordx4) ----
    if (lane < 24) {
        const int c  = lane >> 3;        // 0..2
        const int s4 = lane & 7;
        const float ctr = (c == 0) ? cx : ((c == 1) ? cy : cz);
        f4 o;
        o.x = __fsub_rn(pxyz[w][s4 * 4 + 0][c], ctr);
        o.y = __fsub_rn(pxyz[w][s4 * 4 + 1][c], ctr);
        o.z = __fsub_rn(pxyz[w][s4 * 4 + 2][c], ctr);
        o.w = __fsub_rn(pxyz[w][s4 * 4 + 3][c], ctr);
        __builtin_nontemporal_store(o, (f4*)&ob[(size_t)c * (M_Q * NSAMP) + s4 * 4]);
    }

    // ---- Phase 2b: feature rows (256B contiguous), LDS transpose, dwordx4 nt stores ----
    const float* __restrict__ ftb = ft + (size_t)b * N_PTS * NCH;
    const int sgrp = lane >> 3;          // 0..7
    const int c4   = lane & 7;           // float4 within 32-ch chunk

#pragma unroll
    for (int chunk = 0; chunk < 2; ++chunk) {
        f4 vals[4];
#pragma unroll
        for (int i = 0; i < 4; ++i) {    // 8 lanes x 128B per row-half
            const int s = i * 8 + sgrp;
            const int n = __float_as_int(pxyz[w][s][3]);
            vals[i] = *(const f4*)(ftb + (size_t)n * NCH + chunk * 32 + c4 * 4);
        }
#pragma unroll
        for (int i = 0; i < 4; ++i) {    // [s][c] -> [c][s]  (<=2-way banks: free)
            const int s = i * 8 + sgrp;
            tile[w][c4 * 4 + 0][s] = vals[i].x;
            tile[w][c4 * 4 + 1][s] = vals[i].y;
            tile[w][c4 * 4 + 2][s] = vals[i].z;
            tile[w][c4 * 4 + 3][s] = vals[i].w;
        }
#pragma unroll
        for (int j = 0; j < 4; ++j) {    // 1KB nt store per instr
            const int c_loc = j * 8 + (lane >> 3);
            const int s4    = lane & 7;
            f4 o;
            o.x = tile[w][c_loc][s4 * 4 + 0];
            o.y = tile[w][c_loc][s4 * 4 + 1];
            o.z = tile[w][c_loc][s4 * 4 + 2];
            o.w = tile[w][c_loc][s4 * 4 + 3];
            __builtin_nontemporal_store(
                o, (f4*)&ob[(size_t)(3 + chunk * 32 + c_loc) * (M_Q * NSAMP) + s4 * 4]);
        }
    }
}

// ---------- fallback (ws too small): round-2 direct-gather kernel ----------
__global__ __launch_bounds__(256) void qg_fallback(
    const float* __restrict__ xyz, const float* __restrict__ new_xyz,
    const float* __restrict__ feat, float* __restrict__ out)
{
    const int tid  = threadIdx.x;
    const int w    = tid >> 6;
    const int lane = tid & 63;
    const int q    = blockIdx.x * 4 + w;
    const int b    = q >> 10;
    const int m    = q & (M_Q - 1);

    __shared__ int idx_sh[4][NSAMP];

    const float cx = new_xyz[q * 3 + 0];
    const float cy = new_xyz[q * 3 + 1];
    const float cz = new_xyz[q * 3 + 2];
    const float* __restrict__ xb = xyz + (size_t)b * N_PTS * 3;

    int cnt = 0;
    for (int base = 0; base < N_PTS && cnt < NSAMP; base += 64) {
        const int n = base + lane;
        const float dx = __fsub_rn(cx, xb[n * 3 + 0]);
        const float dy = __fsub_rn(cy, xb[n * 3 + 1]);
        const float dz = __fsub_rn(cz, xb[n * 3 + 2]);
        const float d2 = __fadd_rn(__fadd_rn(__fmul_rn(dx, dx), __fmul_rn(dy, dy)),
                                   __fmul_rn(dz, dz));
        const bool hit = d2 < R2;
        const unsigned long long mk = __ballot(hit);
        if (hit) {
            const int slot = cnt + __popcll(mk & ((1ull << lane) - 1ull));
            if (slot < NSAMP) idx_sh[w][slot] = n;
        }
        cnt += (int)__popcll(mk);
    }
    __syncthreads();
    if (lane < NSAMP) {
        const int v0 = (cnt > 0) ? idx_sh[w][0] : 0;
        if (lane >= cnt) idx_sh[w][lane] = v0;
    }
    __syncthreads();

    const float* __restrict__ fb = feat + (size_t)b * NCH * N_PTS;
    float* __restrict__ ob = out + ((size_t)b * OUT_CH * M_Q + (size_t)m) * NSAMP;
    for (int e = lane; e < OUT_CH * NSAMP; e += 64) {
        const int c = e >> 5, s = e & 31;
        const int n = idx_sh[w][s];
        float v;
        if (c < 3) {
            const float ctr = (c == 0) ? cx : ((c == 1) ? cy : cz);
            v = __fsub_rn(xb[n * 3 + c], ctr);
        } else {
            v = fb[(size_t)(c - 3) * N_PTS + n];
        }
        ob[(size_t)c * (M_Q * NSAMP) + s] = v;
    }
}

extern "C" void kernel_launch(void* const* d_in, const int* in_sizes, int n_in,
                              void* d_out, int out_size, void* d_ws, size_t ws_size,
                              hipStream_t stream) {
    const float* xyz     = (const float*)d_in[0];
    const float* new_xyz = (const float*)d_in[1];
    const float* feat    = (const float*)d_in[2];
    float* out           = (float*)d_out;

    const size_t need = (size_t)B_SZ * N_PTS * NCH * sizeof(float);  // 33.6 MB
    if (ws_size >= need) {
        transpose_kernel<<<B_SZ * (N_PTS / 64), 256, 0, stream>>>(feat, (float*)d_ws);
        qg_main<<<(B_SZ * M_Q) / 4, 256, 0, stream>>>(xyz, new_xyz, (const float*)d_ws, out);
    } else {
        qg_fallback<<<(B_SZ * M_Q) / 4, 256, 0, stream>>>(xyz, new_xyz, feat, out);
    }
}

// Round 6
// 125.557 us; speedup vs baseline: 1.1425x; 1.1425x over previous
//
#include <hip/hip_runtime.h>

// QueryAndGroup: ball_query(r=0.2, ns=32) + group xyz (centered) + group features.
//   xyz      [8][16384][3] f32   d_in[0]
//   new_xyz  [8][1024][3]  f32   d_in[1]
//   features [8][64][16384] f32  d_in[2]
//   out      [8][67][1024][32] f32
//
// R5 evidence: qg_main stuck ~48us regardless of barriers/prefetch/nt-stores;
// FETCH 2.4MB, VALU 12%, HBM 18% -> limiter = VMEM line-request throughput.
// Phase-1 stride-12B xyz loads issue 72 line-requests/iter (24 unique lines).
// R6 fix: SoA coords (xs/ys/zs in d_ws, built inside transpose kernel) ->
// 6 coalesced dword loads = 24 line-requests/iter (unique-line minimum).

#define N_PTS   16384
#define M_Q     1024
#define B_SZ    8
#define NSAMP   32
#define NCH     64
#define R2      0.04f
#define OUT_CH  (3 + NCH)

typedef float f4 __attribute__((ext_vector_type(4)));

// ---------- features [B][C][N] -> ft [B][N][C]; also xyz AoS -> SoA ----------
__global__ __launch_bounds__(256) void transpose_kernel(
    const float* __restrict__ feat, const float* __restrict__ xyz,
    float* __restrict__ ft,
    float* __restrict__ xs, float* __restrict__ ys, float* __restrict__ zs)
{
    __shared__ float tile[64][65];                 // +1 pad
    const int b   = blockIdx.x & 7;                // XCD swizzle: batch = blockIdx % 8
    const int n0  = (blockIdx.x >> 3) << 6;
    const int tid = threadIdx.x;
    const float* __restrict__ fb = feat + (size_t)b * NCH * N_PTS;
    float* __restrict__ tb       = ft   + ((size_t)b * N_PTS + n0) * NCH;

    // SoA coords for this 64-point tile (threads 0..63)
    if (xs && tid < 64) {
        const int p = n0 + tid;
        const float* src = xyz + ((size_t)b * N_PTS + p) * 3;
        xs[(size_t)b * N_PTS + p] = src[0];
        ys[(size_t)b * N_PTS + p] = src[1];
        zs[(size_t)b * N_PTS + p] = src[2];
    }

#pragma unroll
    for (int j = 0; j < 16; ++j) {                 // read coalesced along n (single-use -> nt)
        const int idx = j * 256 + tid;
        const int c = idx >> 6, nn = idx & 63;
        tile[c][nn] = __builtin_nontemporal_load(&fb[(size_t)c * N_PTS + n0 + nn]);
    }
    __syncthreads();
    const int c4 = tid & 15;
    const int r  = tid >> 4;
#pragma unroll
    for (int j = 0; j < 4; ++j) {                  // write: 1KB dwordx4 per instr
        const int nn = j * 16 + r;
        f4 o;
        o.x = tile[c4 * 4 + 0][nn];
        o.y = tile[c4 * 4 + 1][nn];
        o.z = tile[c4 * 4 + 2][nn];
        o.w = tile[c4 * 4 + 3][nn];
        *(f4*)(&tb[(size_t)nn * NCH + c4 * 4]) = o;  // re-read later: keep cached
    }
}

// ---------- main: ball query + grouped gather. SOA: coords from xs/ys/zs ----------
// 4 waves/block, one query per wave, NO __syncthreads (all LDS per-wave).
template <bool SOA>
__global__ __launch_bounds__(256) void qg_main(
    const float* __restrict__ xyz,      // [B][N][3]
    const float* __restrict__ new_xyz,  // [B][M][3]
    const float* __restrict__ ft,       // [B][N][C]
    const float* __restrict__ xs, const float* __restrict__ ys,
    const float* __restrict__ zs,
    float* __restrict__ out)            // [B][67][M][NS]
{
    const int tid  = threadIdx.x;
    const int w    = tid >> 6;
    const int lane = tid & 63;
    const int b    = blockIdx.x & 7;               // XCD swizzle
    const int m    = ((blockIdx.x >> 3) << 2) + w;
    const int q    = (b << 10) + m;

    __shared__ float pxyz[4][NSAMP][4];            // [wave][slot] = {x, y, z, bits(idx)}
    __shared__ float tile[4][32][33];              // [wave][c_local][s]

    const float cx = new_xyz[q * 3 + 0];
    const float cy = new_xyz[q * 3 + 1];
    const float cz = new_xyz[q * 3 + 2];
    const float* __restrict__ xb  = xyz + (size_t)b * N_PTS * 3;
    const float* __restrict__ xsb = SOA ? xs + (size_t)b * N_PTS : nullptr;
    const float* __restrict__ ysb = SOA ? ys + (size_t)b * N_PTS : nullptr;
    const float* __restrict__ zsb = SOA ? zs + (size_t)b * N_PTS : nullptr;

    // ---- Phase 1: ordered ball query, software-pipelined 2x64 chunks ----
    const unsigned long long lmask = (1ull << lane) - 1ull;
    int cnt = 0;
    float Ax, Ay, Az, Bx, By, Bz;
    if (SOA) {
        Ax = xsb[lane];      Ay = ysb[lane];      Az = zsb[lane];
        Bx = xsb[64 + lane]; By = ysb[64 + lane]; Bz = zsb[64 + lane];
    } else {
        Ax = xb[lane * 3 + 0];        Ay = xb[lane * 3 + 1];        Az = xb[lane * 3 + 2];
        Bx = xb[(64 + lane) * 3 + 0]; By = xb[(64 + lane) * 3 + 1]; Bz = xb[(64 + lane) * 3 + 2];
    }

    for (int base = 0; ; base += 128) {
        // prefetch next 128 points before touching this iteration's ballots
        const int  nbase = base + 128;
        const bool more  = nbase < N_PTS;
        const int  pA = more ? nbase + lane : lane;   // dummy reload if done (L1 hit)
        const int  pB = pA + 64;
        float nAx, nAy, nAz, nBx, nBy, nBz;
        if (SOA) {
            nAx = xsb[pA]; nAy = ysb[pA]; nAz = zsb[pA];
            nBx = xsb[pB]; nBy = ysb[pB]; nBz = zsb[pB];
        } else {
            nAx = xb[pA * 3 + 0]; nAy = xb[pA * 3 + 1]; nAz = xb[pA * 3 + 2];
            nBx = xb[pB * 3 + 0]; nBy = xb[pB * 3 + 1]; nBz = xb[pB * 3 + 2];
        }

        {   // chunk A (index order before B)
            const float dx = __fsub_rn(cx, Ax), dy = __fsub_rn(cy, Ay), dz = __fsub_rn(cz, Az);
            const float d2 = __fadd_rn(__fadd_rn(__fmul_rn(dx, dx), __fmul_rn(dy, dy)),
                                       __fmul_rn(dz, dz));
            const bool hit = d2 < R2;
            const unsigned long long mk = __ballot(hit);
            if (hit) {
                const int slot = cnt + __popcll(mk & lmask);
                if (slot < NSAMP) {
                    pxyz[w][slot][0] = Ax;
                    pxyz[w][slot][1] = Ay;
                    pxyz[w][slot][2] = Az;
                    pxyz[w][slot][3] = __int_as_float(base + lane);
                }
            }
            cnt += (int)__popcll(mk);
        }
        {   // chunk B
            const float dx = __fsub_rn(cx, Bx), dy = __fsub_rn(cy, By), dz = __fsub_rn(cz, Bz);
            const float d2 = __fadd_rn(__fadd_rn(__fmul_rn(dx, dx), __fmul_rn(dy, dy)),
                                       __fmul_rn(dz, dz));
            const bool hit = d2 < R2;
            const unsigned long long mk = __ballot(hit);
            if (hit) {
                const int slot = cnt + __popcll(mk & lmask);
                if (slot < NSAMP) {
                    pxyz[w][slot][0] = Bx;
                    pxyz[w][slot][1] = By;
                    pxyz[w][slot][2] = Bz;
                    pxyz[w][slot][3] = __int_as_float(base + 64 + lane);
                }
            }
            cnt += (int)__popcll(mk);
        }
        if (cnt >= NSAMP || !more) break;
        Ax = nAx; Ay = nAy; Az = nAz;
        Bx = nBx; By = nBy; Bz = nBz;
    }

    // fill empty slots with slot 0 (reference broadcasts sorted_idx[...,0])
    if (lane < NSAMP && cnt < NSAMP) {
        float v0x, v0y, v0z, v0w;
        if (cnt > 0) {
            v0x = pxyz[w][0][0]; v0y = pxyz[w][0][1];
            v0z = pxyz[w][0][2]; v0w = pxyz[w][0][3];
        } else {
            v0x = xb[0]; v0y = xb[1]; v0z = xb[2]; v0w = __int_as_float(0);
        }
        if (lane >= cnt) {
            pxyz[w][lane][0] = v0x; pxyz[w][lane][1] = v0y;
            pxyz[w][lane][2] = v0z; pxyz[w][lane][3] = v0w;
        }
    }
    // wave-synchronous: same-wave ds_write -> ds_read ordered by lgkmcnt

    float* __restrict__ ob = out + ((size_t)b * OUT_CH * M_Q + (size_t)m) * NSAMP;

    // ---- Phase 2a: centered xyz channels straight from LDS (24 lanes, 1 dwordx4) ----
    if (lane < 24) {
        const int c  = lane >> 3;        // 0..2
        const int s4 = lane & 7;
        const float ctr = (c == 0) ? cx : ((c == 1) ? cy : cz);
        f4 o;
        o.x = __fsub_rn(pxyz[w][s4 * 4 + 0][c], ctr);
        o.y = __fsub_rn(pxyz[w][s4 * 4 + 1][c], ctr);
        o.z = __fsub_rn(pxyz[w][s4 * 4 + 2][c], ctr);
        o.w = __fsub_rn(pxyz[w][s4 * 4 + 3][c], ctr);
        __builtin_nontemporal_store(o, (f4*)&ob[(size_t)c * (M_Q * NSAMP) + s4 * 4]);
    }

    // ---- Phase 2b: feature rows (256B contiguous), LDS transpose, dwordx4 nt stores ----
    const float* __restrict__ ftb = ft + (size_t)b * N_PTS * NCH;
    const int sgrp = lane >> 3;          // 0..7
    const int c4   = lane & 7;           // float4 within 32-ch chunk

#pragma unroll
    for (int chunk = 0; chunk < 2; ++chunk) {
        f4 vals[4];
#pragma unroll
        for (int i = 0; i < 4; ++i) {    // 8 lanes x 128B per row-half
            const int s = i * 8 + sgrp;
            const int n = __float_as_int(pxyz[w][s][3]);
            vals[i] = *(const f4*)(ftb + (size_t)n * NCH + chunk * 32 + c4 * 4);
        }
#pragma unroll
        for (int i = 0; i < 4; ++i) {    // [s][c] -> [c][s]  (<=2-way banks: free)
            const int s = i * 8 + sgrp;
            tile[w][c4 * 4 + 0][s] = vals[i].x;
            tile[w][c4 * 4 + 1][s] = vals[i].y;
            tile[w][c4 * 4 + 2][s] = vals[i].z;
            tile[w][c4 * 4 + 3][s] = vals[i].w;
        }
#pragma unroll
        for (int j = 0; j < 4; ++j) {    // 1KB nt store per instr
            const int c_loc = j * 8 + (lane >> 3);
            const int s4    = lane & 7;
            f4 o;
            o.x = tile[w][c_loc][s4 * 4 + 0];
            o.y = tile[w][c_loc][s4 * 4 + 1];
            o.z = tile[w][c_loc][s4 * 4 + 2];
            o.w = tile[w][c_loc][s4 * 4 + 3];
            __builtin_nontemporal_store(
                o, (f4*)&ob[(size_t)(3 + chunk * 32 + c_loc) * (M_Q * NSAMP) + s4 * 4]);
        }
    }
}

// ---------- fallback (ws too small): direct-gather kernel ----------
__global__ __launch_bounds__(256) void qg_fallback(
    const float* __restrict__ xyz, const float* __restrict__ new_xyz,
    const float* __restrict__ feat, float* __restrict__ out)
{
    const int tid  = threadIdx.x;
    const int w    = tid >> 6;
    const int lane = tid & 63;
    const int q    = blockIdx.x * 4 + w;
    const int b    = q >> 10;
    const int m    = q & (M_Q - 1);

    __shared__ int idx_sh[4][NSAMP];

    const float cx = new_xyz[q * 3 + 0];
    const float cy = new_xyz[q * 3 + 1];
    const float cz = new_xyz[q * 3 + 2];
    const float* __restrict__ xb = xyz + (size_t)b * N_PTS * 3;

    int cnt = 0;
    for (int base = 0; base < N_PTS && cnt < NSAMP; base += 64) {
        const int n = base + lane;
        const float dx = __fsub_rn(cx, xb[n * 3 + 0]);
        const float dy = __fsub_rn(cy, xb[n * 3 + 1]);
        const float dz = __fsub_rn(cz, xb[n * 3 + 2]);
        const float d2 = __fadd_rn(__fadd_rn(__fmul_rn(dx, dx), __fmul_rn(dy, dy)),
                                   __fmul_rn(dz, dz));
        const bool hit = d2 < R2;
        const unsigned long long mk = __ballot(hit);
        if (hit) {
            const int slot = cnt + __popcll(mk & ((1ull << lane) - 1ull));
            if (slot < NSAMP) idx_sh[w][slot] = n;
        }
        cnt += (int)__popcll(mk);
    }
    __syncthreads();
    if (lane < NSAMP) {
        const int v0 = (cnt > 0) ? idx_sh[w][0] : 0;
        if (lane >= cnt) idx_sh[w][lane] = v0;
    }
    __syncthreads();

    const float* __restrict__ fb = feat + (size_t)b * NCH * N_PTS;
    float* __restrict__ ob = out + ((size_t)b * OUT_CH * M_Q + (size_t)m) * NSAMP;
    for (int e = lane; e < OUT_CH * NSAMP; e += 64) {
        const int c = e >> 5, s = e & 31;
        const int n = idx_sh[w][s];
        float v;
        if (c < 3) {
            const float ctr = (c == 0) ? cx : ((c == 1) ? cy : cz);
            v = __fsub_rn(xb[n * 3 + c], ctr);
        } else {
            v = fb[(size_t)(c - 3) * N_PTS + n];
        }
        ob[(size_t)c * (M_Q * NSAMP) + s] = v;
    }
}

extern "C" void kernel_launch(void* const* d_in, const int* in_sizes, int n_in,
                              void* d_out, int out_size, void* d_ws, size_t ws_size,
                              hipStream_t stream) {
    const float* xyz     = (const float*)d_in[0];
    const float* new_xyz = (const float*)d_in[1];
    const float* feat    = (const float*)d_in[2];
    float* out           = (float*)d_out;

    const size_t ft_elems  = (size_t)B_SZ * N_PTS * NCH;        // 8388608
    const size_t soa_elems = (size_t)B_SZ * N_PTS;              // 131072
    const size_t need_soa  = (ft_elems + 3 * soa_elems) * sizeof(float);  // ~35.1 MB
    const size_t need_ft   = ft_elems * sizeof(float);                    // 33.6 MB

    float* ft = (float*)d_ws;
    float* xs = ft + ft_elems;
    float* ys = xs + soa_elems;
    float* zs = ys + soa_elems;

    if (ws_size >= need_soa) {
        transpose_kernel<<<B_SZ * (N_PTS / 64), 256, 0, stream>>>(feat, xyz, ft, xs, ys, zs);
        qg_main<true><<<(B_SZ * M_Q) / 4, 256, 0, stream>>>(
            xyz, new_xyz, ft, xs, ys, zs, out);
    } else if (ws_size >= need_ft) {
        transpose_kernel<<<B_SZ * (N_PTS / 64), 256, 0, stream>>>(
            feat, xyz, ft, nullptr, nullptr, nullptr);
        qg_main<false><<<(B_SZ * M_Q) / 4, 256, 0, stream>>>(
            xyz, new_xyz, ft, nullptr, nullptr, nullptr, out);
    } else {
        qg_fallback<<<(B_SZ * M_Q) / 4, 256, 0, stream>>>(xyz, new_xyz, feat, out);
    }
}